// Round 16
// baseline (173.783 us; speedup 1.0000x reference)
//
#include <hip/hip_runtime.h>
#include <hip/hip_bf16.h>

#define NIN 1024
#define NL 128
#define MS 16384    // 128x128 matrix slot (elements)
#define CMS 32768   // 256x128 C slot (elements)

typedef __attribute__((ext_vector_type(8))) short bf16x8_t;
typedef __attribute__((ext_vector_type(4))) float f32x4_t;

__device__ inline unsigned short f2bf(float f) {
    __hip_bfloat16 h = __float2bfloat16(f);
    return *reinterpret_cast<unsigned short*>(&h);
}
__device__ inline ushort4 pack4(f32x4_t v) {
    ushort4 o;
    o.x = f2bf(v[0]); o.y = f2bf(v[1]); o.z = f2bf(v[2]); o.w = f2bf(v[3]);
    return o;
}

// ---- stage a 128x128 f32 matrix into LDS (64 KB) ---------------------------
__device__ __forceinline__ void stageS(const float* __restrict__ Sg, float* S) {
    int t = threadIdx.x;
    for (int i = t; i < 4096; i += 256)
        ((f32x4_t*)S)[i] = ((const f32x4_t*)Sg)[i];
}

// ---- M = S @ S, both full 128x128 in LDS (VALU, ~3.4us) --------------------
__device__ __forceinline__ void sq128(const float* S, float* M) {
    int t = threadIdx.x;
    int j0 = (t & 31) * 4, rh = t >> 5;  // 8 row-groups x 16 rows
    f32x4_t acc[16];
#pragma unroll
    for (int rr = 0; rr < 16; ++rr) acc[rr] = (f32x4_t){0.f, 0.f, 0.f, 0.f};
    for (int k0 = 0; k0 < 32; ++k0) {
        f32x4_t cv[4];
#pragma unroll
        for (int kx = 0; kx < 4; ++kx)
            cv[kx] = *(const f32x4_t*)&S[(k0 * 4 + kx) * 128 + j0];
#pragma unroll
        for (int rr = 0; rr < 16; ++rr) {
            f32x4_t av = *(const f32x4_t*)&S[(rh * 16 + rr) * 128 + k0 * 4];
            acc[rr] += av.x * cv[0] + av.y * cv[1] + av.z * cv[2] + av.w * cv[3];
        }
    }
#pragma unroll
    for (int rr = 0; rr < 16; ++rr)
        *(f32x4_t*)&M[(rh * 16 + rr) * 128 + j0] = acc[rr];
}

// ---- D[0..16)x128 = A[0..16)x128 @ B(128x128); generic pointers ------------
__device__ __forceinline__ void mm16_core(const float* A, const float* B,
                                          f32x4_t& o0, f32x4_t& o1) {
    int t = threadIdx.x;
    int j0 = (t & 31) * 4, rh = t >> 5;  // 2 rows per thread
    f32x4_t a0 = (f32x4_t){0.f, 0.f, 0.f, 0.f}, a1 = a0;
    for (int k0 = 0; k0 < 32; ++k0) {
        f32x4_t cv[4];
#pragma unroll
        for (int kx = 0; kx < 4; ++kx)
            cv[kx] = *(const f32x4_t*)&B[(k0 * 4 + kx) * 128 + j0];
        f32x4_t av0 = *(const f32x4_t*)&A[(rh * 2 + 0) * 128 + k0 * 4];
        f32x4_t av1 = *(const f32x4_t*)&A[(rh * 2 + 1) * 128 + k0 * 4];
        a0 += av0.x * cv[0] + av0.y * cv[1] + av0.z * cv[2] + av0.w * cv[3];
        a1 += av1.x * cv[0] + av1.y * cv[1] + av1.z * cv[2] + av1.w * cv[3];
    }
    o0 = a0; o1 = a1;
}
__device__ __forceinline__ void mm16(const float* A, const float* B,
                                     float* D, unsigned short* Db) {
    f32x4_t a0, a1;
    mm16_core(A, B, a0, a1);
    int t = threadIdx.x;
    int j0 = (t & 31) * 4, rh = t >> 5;
    *(f32x4_t*)&D[(rh * 2 + 0) * 128 + j0] = a0;
    *(f32x4_t*)&D[(rh * 2 + 1) * 128 + j0] = a1;
    if (Db) {
        *(ushort4*)&Db[(rh * 2 + 0) * 128 + j0] = pack4(a0);
        *(ushort4*)&Db[(rh * 2 + 1) * 128 + j0] = pack4(a1);
    }
}
// two-stage: D = (A@B1)@B2, bouncing the 16x128 intermediate through Sbuf
__device__ __forceinline__ void mm16_two(const float* A, const float* B1,
                                         const float* B2, float* Sbuf,
                                         float* D, unsigned short* Db) {
    f32x4_t a0, a1;
    mm16_core(A, B1, a0, a1);
    __syncthreads();  // all reads of B1 (=Sbuf region) complete
    int t = threadIdx.x;
    int j0 = (t & 31) * 4, rh = t >> 5;
    *(f32x4_t*)&Sbuf[(rh * 2 + 0) * 128 + j0] = a0;
    *(f32x4_t*)&Sbuf[(rh * 2 + 1) * 128 + j0] = a1;
    __syncthreads();
    mm16(Sbuf, B2, D, Db);
}
// copy 16 rows of LDS matrix M (abs rows r0..) to global f32 (+bf16)
__device__ __forceinline__ void copy16(const float* M, int r0,
                                       float* Wd, unsigned short* Wbd) {
    int t = threadIdx.x;
    for (int i = t; i < 512; i += 256) {
        int rr = i >> 5, c4 = (i & 31) * 4;
        f32x4_t v = *(const f32x4_t*)&M[(r0 + rr) * 128 + c4];
        *(f32x4_t*)&Wd[(r0 + rr) * 128 + c4] = v;
        if (Wbd) *(ushort4*)&Wbd[(r0 + rr) * 128 + c4] = pack4(v);
    }
}

// f32 tile: D[r0..r0+32)[j0..j0+64) = A_rows @ B(128x128); optional bf16 copy.
__device__ __forceinline__ void pmm32x64(const float* __restrict__ A,
                                         const float* __restrict__ B,
                                         float* __restrict__ D,
                                         unsigned short* __restrict__ Db,
                                         int r0, int j0, char* lds) {
    float* Bl = (float*)lds;                        // [128][64] 32 KB
    float (*At)[36] = (float(*)[36])(lds + 32768);  // [128][36] 18 KB
    int t = threadIdx.x;
    for (int idx = t; idx < 2048; idx += 256) {
        int row = idx >> 4, c = idx & 15;
        *(float4*)&Bl[row * 64 + c * 4] = *(const float4*)&B[row * NL + j0 + c * 4];
    }
    for (int idx = t; idx < 4096; idx += 256) {
        int m = idx >> 7, kk = idx & 127;
        At[kk][m] = A[(size_t)(r0 + m) * NL + kk];
    }
    __syncthreads();
    int j = t & 63, rg = t >> 6;
    float acc[8];
#pragma unroll
    for (int q = 0; q < 8; ++q) acc[q] = 0.f;
#pragma unroll 4
    for (int kk = 0; kk < NL; ++kk) {
        float bv = Bl[kk * 64 + j];
        const f32x4_t* ap = (const f32x4_t*)&At[kk][rg * 8];
        f32x4_t a0 = ap[0], a1 = ap[1];
        acc[0] += a0[0] * bv; acc[1] += a0[1] * bv;
        acc[2] += a0[2] * bv; acc[3] += a0[3] * bv;
        acc[4] += a1[0] * bv; acc[5] += a1[1] * bv;
        acc[6] += a1[2] * bv; acc[7] += a1[3] * bv;
    }
#pragma unroll
    for (int q = 0; q < 8; ++q) {
        size_t off = (size_t)(r0 + rg * 8 + q) * NL + j0 + j;
        D[off] = acc[q];
        if (Db) Db[off] = f2bf(acc[q]);
    }
}

// H tile (bf16 MFMA, swapped operands): H[(n*16+a)][m] = sum_l F[n,l]*T^{a+1}[m,l]
__device__ __forceinline__ void hmfma(const unsigned short* __restrict__ Fb,
                                      const unsigned short* __restrict__ Wa,
                                      unsigned short* __restrict__ H,
                                      int a, int nt, char* lds) {
    char* lB = lds;  // swizzled T tile, 32 KB
    int t = threadIdx.x;
    for (int i = t; i < 2048; i += 256) {
        int row = i >> 4, c = i & 15;
        int sw = (c * 16) ^ ((row & 7) << 4);
        *(bf16x8_t*)(lB + row * 256 + sw) = *(const bf16x8_t*)(Wa + (size_t)row * NL + c * 8);
    }
    __syncthreads();
    int w = t >> 6, lane = t & 63;
    int wn = (w >> 1) * 64, wm = (w & 1) * 64;
    int r = lane & 15, g = lane >> 4;
    const unsigned short* Ag = Fb + (size_t)(nt * 128) * NL;
    bf16x8_t av[4][4];  // [kk][aa]
#pragma unroll
    for (int kk = 0; kk < 4; ++kk) {
        int c16 = kk * 4 + g;
#pragma unroll
        for (int aa = 0; aa < 4; ++aa)
            av[kk][aa] = *(const bf16x8_t*)(Ag + (size_t)(wn + aa * 16 + r) * NL + c16 * 8);
    }
    f32x4_t acc[4][4];
#pragma unroll
    for (int aa = 0; aa < 4; ++aa)
#pragma unroll
        for (int bb = 0; bb < 4; ++bb) acc[aa][bb] = (f32x4_t){0.f, 0.f, 0.f, 0.f};
#pragma unroll
    for (int kk = 0; kk < 4; ++kk) {
        int c16 = kk * 4 + g;
        bf16x8_t bv[4];
#pragma unroll
        for (int bb = 0; bb < 4; ++bb) {
            int rowB = wm + bb * 16 + r;
            bv[bb] = *(const bf16x8_t*)(lB + rowB * 256 + ((c16 * 16) ^ ((rowB & 7) << 4)));
        }
#pragma unroll
        for (int aa = 0; aa < 4; ++aa)
#pragma unroll
            for (int bb = 0; bb < 4; ++bb)
                acc[aa][bb] = __builtin_amdgcn_mfma_f32_16x16x32_bf16(bv[bb], av[kk][aa], acc[aa][bb], 0, 0, 0);
    }
#pragma unroll
    for (int aa = 0; aa < 4; ++aa) {
        int n = nt * 128 + wn + aa * 16 + r;
#pragma unroll
        for (int bb = 0; bb < 4; ++bb) {
            int m0 = wm + bb * 16 + g * 4;
            ushort4 o;
            o.x = f2bf(acc[aa][bb][0]); o.y = f2bf(acc[aa][bb][1]);
            o.z = f2bf(acc[aa][bb][2]); o.w = f2bf(acc[aa][bb][3]);
            *(ushort4*)&H[((size_t)n * 16 + a) * NL + m0] = o;
        }
    }
}

// ---------------- preamble: 5 phases (square-and-extend redundancy) ---------
// W slots: 0..15 = T^1..T^16, 16 = T^32, 17 = T^64, 18 = T^128
// ph0 (200): lat0(128) | tr->W0/Wb0, tf->Fb (64) | sqx: T2,T3,T4 (8)
// ph1 (96):  T5..8 = T^{1..4}@T4 pmm(32) | T9..16 via redundant T8 (64)
// ph2 (152): sqx: T32,T64 (8) | C1 pmm(16) | H(128)
// ph3 (104): C2,3 (32) | C4,5 (32) | C6,7 = C0,1@T32@T64 (32) | T128 (8)
// ph4 (128): C8..15 = C0..7 @ T128
__global__ __launch_bounds__(256) void k_phase(int ph,
                                               const float* __restrict__ x,
                                               const float* __restrict__ tf,
                                               const float* __restrict__ tr,
                                               float* __restrict__ W,
                                               unsigned short* __restrict__ Wb,
                                               unsigned short* __restrict__ Fb,
                                               float* __restrict__ Cf,
                                               unsigned short* __restrict__ Cc,
                                               unsigned short* __restrict__ H) {
    __shared__ __align__(16) char lds[131072];
    float* S = (float*)lds;             // 64 KB
    float* M = (float*)(lds + 65536);   // 64 KB
    int blk = blockIdx.x, t = threadIdx.x;
    if (ph == 0) {
        if (blk < 128) {
            float* xr = (float*)lds;  // [2][1024]
            int b0 = blk * 2;
            for (int idx = t; idx < 512; idx += 256) {
                int rr = idx >> 8, c = idx & 255;
                ((float4*)xr)[rr * 256 + c] =
                    ((const float4*)(x + (size_t)(b0 + rr) * NIN))[c];
            }
            __syncthreads();
            int rr = t >> 7, col = t & 127;
            const float* xp = xr + rr * NIN;
            float a = 0.f;
#pragma unroll 8
            for (int i = 0; i < NIN; ++i) a += xp[i] * tf[i * NL + col];
            Cf[(size_t)(b0 + rr) * NL + col] = a;
            Cc[(size_t)(b0 + rr) * NL + col] = f2bf(a);
        } else if (blk < 192) {
            int id = (blk - 128) * 256 + t;  // 0..16383
            float v = tr[id];
            W[id] = v;
            Wb[id] = f2bf(v);
            for (int i = id; i < NIN * NL; i += 16384) Fb[i] = f2bf(tf[i]);
        } else {
            // sqx0: M = T2; emit T2, T3 = T2@T1, T4 = T2@T2 (16 rows each)
            int r0 = (blk - 192) * 16;
            stageS(tr, S);
            __syncthreads();
            sq128(S, M);
            __syncthreads();
            copy16(M, r0, W + MS, Wb + MS);
            mm16(M + r0 * 128, S, W + 2 * (size_t)MS + r0 * 128, Wb + 2 * (size_t)MS + r0 * 128);
            mm16(M + r0 * 128, M, W + 3 * (size_t)MS + r0 * 128, Wb + 3 * (size_t)MS + r0 * 128);
        }
    } else if (ph == 1) {
        if (blk < 32) {
            // T^{5..8} = T^{1..4} @ T^4
            int i = blk >> 3, tt = blk & 7;
            pmm32x64(W + (size_t)i * MS, W + 3 * (size_t)MS,
                     W + (size_t)(4 + i) * MS, Wb + (size_t)(4 + i) * MS,
                     ((tt >> 1) & 3) * 32, (tt & 1) * 64, lds);
        } else {
            // redundant T8 = T4@T4; emit T^{9..16}
            int rel = blk - 32, mo = rel >> 3, r0 = (rel & 7) * 16;
            stageS(W + 3 * (size_t)MS, S);  // S = T4
            __syncthreads();
            sq128(S, M);                     // M = T8
            __syncthreads();
            if (mo < 4) {        // T^{9..12} = T^{1..4} @ T8
                mm16(W + (size_t)mo * MS + r0 * 128, M,
                     W + (size_t)(8 + mo) * MS + r0 * 128,
                     Wb + (size_t)(8 + mo) * MS + r0 * 128);
            } else if (mo < 7) { // T^{13..15} = T^{1..3} @ T4 @ T8
                int i = mo - 4;
                mm16_two(W + (size_t)i * MS + r0 * 128, S, M, S,
                         W + (size_t)(8 + mo) * MS + r0 * 128,
                         Wb + (size_t)(8 + mo) * MS + r0 * 128);
            } else {             // T^16 = T8 @ T8
                mm16(M + r0 * 128, M, W + 15 * (size_t)MS + r0 * 128,
                     Wb + 15 * (size_t)MS + r0 * 128);
            }
        }
    } else if (ph == 2) {
        if (blk < 8) {
            // sqx64: M = T32; emit T32, T64 = T32@T32
            int r0 = blk * 16;
            stageS(W + 15 * (size_t)MS, S);  // S = T16
            __syncthreads();
            sq128(S, M);                      // M = T32
            __syncthreads();
            copy16(M, r0, W + 16 * (size_t)MS, nullptr);
            mm16(M + r0 * 128, M, W + 17 * (size_t)MS + r0 * 128, nullptr);
        } else if (blk < 24) {
            // C1 = C0 @ T16
            int tt = blk - 8;
            pmm32x64(Cf, W + 15 * (size_t)MS, Cf + CMS, Cc + CMS,
                     (tt >> 1) * 32, (tt & 1) * 64, lds);
        } else {
            int rel = blk - 24;
            hmfma(Fb, Wb + (size_t)(rel >> 3) * MS, H, rel >> 3, rel & 7, lds);
        }
    } else if (ph == 3) {
        if (blk < 32) {
            // C2,3 = C0,1 @ T32
            int q = blk >> 4, tt = blk & 15;
            pmm32x64(Cf + (size_t)q * CMS, W + 16 * (size_t)MS,
                     Cf + (size_t)(2 + q) * CMS, Cc + (size_t)(2 + q) * CMS,
                     (tt >> 1) * 32, (tt & 1) * 64, lds);
        } else if (blk < 64) {
            // C4,5 = C0,1 @ T64
            int rel = blk - 32, q = rel >> 4, tt = rel & 15;
            pmm32x64(Cf + (size_t)q * CMS, W + 17 * (size_t)MS,
                     Cf + (size_t)(4 + q) * CMS, Cc + (size_t)(4 + q) * CMS,
                     (tt >> 1) * 32, (tt & 1) * 64, lds);
        } else if (blk < 96) {
            // C6,7 = C0,1 @ T32 @ T64 (two-stage; B2 = T64 read from global)
            int rel = blk - 64, q = rel >> 4, r0 = (rel & 15) * 16;
            stageS(W + 16 * (size_t)MS, S);  // S = T32
            __syncthreads();
            mm16_two(Cf + (size_t)q * CMS + r0 * 128, S, W + 17 * (size_t)MS, S,
                     Cf + (size_t)(6 + q) * CMS + r0 * 128,
                     Cc + (size_t)(6 + q) * CMS + r0 * 128);
        } else {
            // T128 = T64 @ T64
            int tt = blk - 96;
            pmm32x64(W + 17 * (size_t)MS, W + 17 * (size_t)MS,
                     W + 18 * (size_t)MS, nullptr,
                     ((tt >> 1) & 3) * 32, (tt & 1) * 64, lds);
        }
    } else {
        // C8..15 = C0..7 @ T128
        int q = blk >> 4, tt = blk & 15;
        pmm32x64(Cf + (size_t)q * CMS, W + 18 * (size_t)MS,
                 Cf + (size_t)(8 + q) * CMS, Cc + (size_t)(8 + q) * CMS,
                 (tt >> 1) * 32, (tt & 1) * 64, lds);
    }
}

// ---------------- k_main: out = Cc_j @ H^T (identical to R15) ---------------
__global__ __launch_bounds__(256) void k_main(const unsigned short* __restrict__ Cc,
                                              const unsigned short* __restrict__ H,
                                              float* __restrict__ out) {
    int bid = blockIdx.x;
    int e = ((bid & 7) << 6) | (bid >> 3);  // XCD gets contiguous span
    int ct = e >> 2, bt = (e >> 1) & 1, jh = e & 1;
    __shared__ __align__(16) char lds[49152];
    char* lB = lds;  // 32 KB swizzled H tile
    int t = threadIdx.x;
    const unsigned short* Bg = H + (size_t)(ct * 128) * NL;
    for (int i = t; i < 2048; i += 256) {
        int row = i >> 4, c = i & 15;
        int sw = (c * 16) ^ ((row & 7) << 4);
        *(bf16x8_t*)(lB + row * 256 + sw) =
            *(const bf16x8_t*)(Bg + (size_t)row * NL + c * 8);
    }
    __syncthreads();
    int w = t >> 6, lane = t & 63;
    int wr = (w >> 1) * 64;   // wave b-row offset
    int wc = (w & 1) * 64;    // wave col offset
    int r = lane & 15, g = lane >> 4;
    char* slab = lds + 32768 + w * 4096;  // wave-private 4 KB bounce

    for (int mf = 0; mf < 4; ++mf) {
        int brow_base = bt * 128 + wr + mf * 16;
#pragma unroll
        for (int g0 = 0; g0 < 2; ++g0) {
            for (int nf = 0; nf < 4; ++nf) {
                int nn = (w & 1) * 4 + nf;
                int rowB = wc + nf * 16 + r;
                f32x4_t acc4[4];
#pragma unroll
                for (int q = 0; q < 4; ++q) acc4[q] = (f32x4_t){0.f, 0.f, 0.f, 0.f};
#pragma unroll
                for (int jj4 = 0; jj4 < 4; ++jj4) {
                    int j = jh * 8 + g0 * 4 + jj4;
                    const unsigned short* Arow =
                        Cc + (size_t)j * CMS + (size_t)(brow_base + r) * NL;
#pragma unroll
                    for (int kk = 0; kk < 4; ++kk) {
                        bf16x8_t av = *(const bf16x8_t*)(Arow + (kk * 4 + g) * 8);
                        bf16x8_t bvv = *(const bf16x8_t*)(
                            lB + rowB * 256 + (((kk * 4 + g) * 16) ^ ((rowB & 7) << 4)));
                        acc4[jj4] = __builtin_amdgcn_mfma_f32_16x16x32_bf16(
                            bvv, av, acc4[jj4], 0, 0, 0);
                    }
                }
#pragma unroll
                for (int jj4 = 0; jj4 < 4; ++jj4) {
                    int boff = r * 256 + ((jj4 * 64 + g * 16 + r * 32) & 255);
                    *(f32x4_t*)(slab + boff) = acc4[jj4];
                }
#pragma unroll
                for (int i2 = 0; i2 < 4; ++i2) {
                    int lin = i2 * 1024 + lane * 16;
                    int rs = lin >> 8, cb = lin & 255;
                    f32x4_t v = *(const f32x4_t*)(slab + rs * 256 + ((cb + rs * 32) & 255));
                    size_t o = (size_t)(brow_base + rs) * (NIN * 256) +
                               (size_t)(ct * 8 + nn) * 256 + jh * 128 + g0 * 64 + (cb >> 2);
                    *(f32x4_t*)&out[o] = v;
                }
            }
        }
    }
}

extern "C" void kernel_launch(void* const* d_in, const int* in_sizes, int n_in,
                              void* d_out, int out_size, void* d_ws, size_t ws_size,
                              hipStream_t stream) {
    const float* x = (const float*)d_in[0];
    const float* tf = (const float*)d_in[1];
    const float* tr = (const float*)d_in[2];
    float* out = (float*)d_out;

    // workspace (~9 MB)
    float* W = (float*)d_ws;                              // 20 f32 slots
    float* Cf = W + (size_t)20 * MS;                      // 16 x [256][128] f32
    unsigned short* Wb = (unsigned short*)(Cf + (size_t)16 * CMS);  // 16 bf16 slots
    unsigned short* Fb = Wb + (size_t)16 * MS;            // [1024][128] bf16
    unsigned short* Cc = Fb + (size_t)NIN * NL;           // 16 x [256][128] bf16
    unsigned short* H = Cc + (size_t)16 * CMS;            // [16384][128] bf16 (4 MB)

    static const int grids[5] = {200, 96, 152, 104, 128};
    for (int ph = 0; ph < 5; ++ph) {
        k_phase<<<grids[ph], 256, 0, stream>>>(ph, x, tf, tr, W, Wb, Fb,
                                               Cf, Cc, H);
    }
    k_main<<<512, 256, 0, stream>>>(Cc, H, out);
}

// Round 17
// 149.652 us; speedup vs baseline: 1.1612x; 1.1612x over previous
//
#include <hip/hip_runtime.h>
#include <hip/hip_bf16.h>

#define NIN 1024
#define NL 128
#define MS 16384    // 128x128 matrix slot (elements)
#define CMS 32768   // 256x128 C slot (elements)

typedef __attribute__((ext_vector_type(8))) short bf16x8_t;
typedef __attribute__((ext_vector_type(4))) float f32x4_t;

__device__ inline unsigned short f2bf(float f) {
    __hip_bfloat16 h = __float2bfloat16(f);
    return *reinterpret_cast<unsigned short*>(&h);
}
__device__ inline ushort4 pack4(f32x4_t v) {
    ushort4 o;
    o.x = f2bf(v[0]); o.y = f2bf(v[1]); o.z = f2bf(v[2]); o.w = f2bf(v[3]);
    return o;
}

// f32 tile: D[r0..r0+32)[j0..j0+64) = A_rows @ B(128x128); optional bf16 copy.
__device__ __forceinline__ void pmm32x64(const float* __restrict__ A,
                                         const float* __restrict__ B,
                                         float* __restrict__ D,
                                         unsigned short* __restrict__ Db,
                                         int r0, int j0, char* lds) {
    float* Bl = (float*)lds;                        // [128][64] 32 KB
    float (*At)[36] = (float(*)[36])(lds + 32768);  // [128][36] 18 KB
    int t = threadIdx.x;
    for (int idx = t; idx < 2048; idx += 256) {
        int row = idx >> 4, c = idx & 15;
        *(float4*)&Bl[row * 64 + c * 4] = *(const float4*)&B[row * NL + j0 + c * 4];
    }
    for (int idx = t; idx < 4096; idx += 256) {
        int m = idx >> 7, kk = idx & 127;
        At[kk][m] = A[(size_t)(r0 + m) * NL + kk];
    }
    __syncthreads();
    int j = t & 63, rg = t >> 6;
    float acc[8];
#pragma unroll
    for (int q = 0; q < 8; ++q) acc[q] = 0.f;
#pragma unroll 4
    for (int kk = 0; kk < NL; ++kk) {
        float bv = Bl[kk * 64 + j];
        const f32x4_t* ap = (const f32x4_t*)&At[kk][rg * 8];
        f32x4_t a0 = ap[0], a1 = ap[1];
        acc[0] += a0[0] * bv; acc[1] += a0[1] * bv;
        acc[2] += a0[2] * bv; acc[3] += a0[3] * bv;
        acc[4] += a1[0] * bv; acc[5] += a1[1] * bv;
        acc[6] += a1[2] * bv; acc[7] += a1[3] * bv;
    }
#pragma unroll
    for (int q = 0; q < 8; ++q) {
        size_t off = (size_t)(r0 + rg * 8 + q) * NL + j0 + j;
        D[off] = acc[q];
        if (Db) Db[off] = f2bf(acc[q]);
    }
}

// H tile (bf16 MFMA, swapped operands): H[(n*16+a)][m] = sum_l F[n,l]*T^{a+1}[m,l]
__device__ __forceinline__ void hmfma(const unsigned short* __restrict__ Fb,
                                      const unsigned short* __restrict__ Wa,
                                      unsigned short* __restrict__ H,
                                      int a, int nt, char* lds) {
    char* lB = lds;  // swizzled T tile, 32 KB
    int t = threadIdx.x;
    for (int i = t; i < 2048; i += 256) {
        int row = i >> 4, c = i & 15;
        int sw = (c * 16) ^ ((row & 7) << 4);
        *(bf16x8_t*)(lB + row * 256 + sw) = *(const bf16x8_t*)(Wa + (size_t)row * NL + c * 8);
    }
    __syncthreads();
    int w = t >> 6, lane = t & 63;
    int wn = (w >> 1) * 64, wm = (w & 1) * 64;
    int r = lane & 15, g = lane >> 4;
    const unsigned short* Ag = Fb + (size_t)(nt * 128) * NL;
    bf16x8_t av[4][4];  // [kk][aa]
#pragma unroll
    for (int kk = 0; kk < 4; ++kk) {
        int c16 = kk * 4 + g;
#pragma unroll
        for (int aa = 0; aa < 4; ++aa)
            av[kk][aa] = *(const bf16x8_t*)(Ag + (size_t)(wn + aa * 16 + r) * NL + c16 * 8);
    }
    f32x4_t acc[4][4];
#pragma unroll
    for (int aa = 0; aa < 4; ++aa)
#pragma unroll
        for (int bb = 0; bb < 4; ++bb) acc[aa][bb] = (f32x4_t){0.f, 0.f, 0.f, 0.f};
#pragma unroll
    for (int kk = 0; kk < 4; ++kk) {
        int c16 = kk * 4 + g;
        bf16x8_t bv[4];
#pragma unroll
        for (int bb = 0; bb < 4; ++bb) {
            int rowB = wm + bb * 16 + r;
            bv[bb] = *(const bf16x8_t*)(lB + rowB * 256 + ((c16 * 16) ^ ((rowB & 7) << 4)));
        }
#pragma unroll
        for (int aa = 0; aa < 4; ++aa)
#pragma unroll
            for (int bb = 0; bb < 4; ++bb)
                acc[aa][bb] = __builtin_amdgcn_mfma_f32_16x16x32_bf16(bv[bb], av[kk][aa], acc[aa][bb], 0, 0, 0);
    }
#pragma unroll
    for (int aa = 0; aa < 4; ++aa) {
        int n = nt * 128 + wn + aa * 16 + r;
#pragma unroll
        for (int bb = 0; bb < 4; ++bb) {
            int m0 = wm + bb * 16 + g * 4;
            *(ushort4*)&H[((size_t)n * 16 + a) * NL + m0] = pack4(acc[aa][bb]);
        }
    }
}

// ---------------- one preamble phase per launch (R15 structure) -------------
// ph0 (104): lat0 32 blk (8 rows ea, f32x4 tf loads) | copy 64 | T2 8
// ph1..3: T-chain to T^16; ph4 (152): T32|C1|H; ph5 (40): T64|C2,3;
// ph6 (72): T128|C4..7; ph7 (136): C8..15
__global__ __launch_bounds__(256) void k_phase(int ph,
                                               const float* __restrict__ x,
                                               const float* __restrict__ tf,
                                               const float* __restrict__ tr,
                                               float* __restrict__ W,
                                               unsigned short* __restrict__ Wb,
                                               unsigned short* __restrict__ Fb,
                                               float* __restrict__ Cf,
                                               unsigned short* __restrict__ Cc,
                                               unsigned short* __restrict__ H) {
    __shared__ __align__(16) char lds[51200];
    int blk = blockIdx.x, t = threadIdx.x;
    if (ph == 0) {
        if (blk < 32) {
            // lat0: 8 b-rows per block; thread owns 4 cols (f32x4 tf loads)
            float* xr = (float*)lds;  // [8][1024] 32 KB
            int b0 = blk * 8;
            for (int idx = t; idx < 2048; idx += 256) {
                int rr = idx >> 8, c = idx & 255;
                ((float4*)xr)[rr * 256 + c] =
                    ((const float4*)(x + (size_t)(b0 + rr) * NIN))[c];
            }
            __syncthreads();
            int cg = t & 31, rs = t >> 5;
            const float* xp = xr + rs * NIN;
            f32x4_t acc = (f32x4_t){0.f, 0.f, 0.f, 0.f};
#pragma unroll 8
            for (int i = 0; i < NIN; ++i) {
                f32x4_t tv = *(const f32x4_t*)&tf[i * NL + cg * 4];
                acc += xp[i] * tv;
            }
            int row = b0 + rs;
            *(f32x4_t*)&Cf[(size_t)row * NL + cg * 4] = acc;
            *(ushort4*)&Cc[(size_t)row * NL + cg * 4] = pack4(acc);
        } else if (blk < 96) {
            int id = (blk - 32) * 256 + t;  // 0..16383
            float v = tr[id];
            W[id] = v;
            Wb[id] = f2bf(v);
            for (int i = id; i < NIN * NL; i += 16384) Fb[i] = f2bf(tf[i]);
        } else {
            int tt = blk - 96;  // T^2 = tr @ tr -> slot 1
            pmm32x64(tr, tr, W + MS, Wb + MS,
                     ((tt >> 1) & 3) * 32, (tt & 1) * 64, lds);
        }
    } else if (ph <= 3) {
        int m = 2 << (ph - 1);  // 2,4,8
        int i = blk >> 3, tt = blk & 7;
        pmm32x64(W + (size_t)i * MS, W + (size_t)(m - 1) * MS,
                 W + (size_t)(m + i) * MS, Wb + (size_t)(m + i) * MS,
                 ((tt >> 1) & 3) * 32, (tt & 1) * 64, lds);
    } else {
        int lv = ph - 4;    // 0..3
        int b2s = 15 + lv;  // W slot of T^{16<<lv}
        int ncp = 1 << lv;
        if (lv < 3 && blk < 8) {
            pmm32x64(W + (size_t)b2s * MS, W + (size_t)b2s * MS,
                     W + (size_t)(16 + lv) * MS, nullptr,
                     ((blk >> 1) & 3) * 32, (blk & 1) * 64, lds);
        } else if (blk >= 8 && blk < 8 + ncp * 16) {
            int rel = blk - 8, q = rel >> 4, tt = rel & 15;
            pmm32x64(Cf + (size_t)q * CMS, W + (size_t)b2s * MS,
                     Cf + (size_t)(ncp + q) * CMS, Cc + (size_t)(ncp + q) * CMS,
                     (tt >> 1) * 32, (tt & 1) * 64, lds);
        } else if (lv == 0 && blk >= 24 && blk < 152) {
            int rel = blk - 24;
            hmfma(Fb, Wb + (size_t)(rel >> 3) * MS, H, rel >> 3, rel & 7, lds);
        }
    }
}

// ---------------- k_main: out = Cc_j @ H^T ----------------------------------
// av hoisted per (mf,g0), bv hoisted per nf -> 4x fewer L2/LDS reads than R15.
// 4KB/wave rotation-swizzled bounce slab; contiguous normal stores; 48KB LDS.
__global__ __launch_bounds__(256) void k_main(const unsigned short* __restrict__ Cc,
                                              const unsigned short* __restrict__ H,
                                              float* __restrict__ out) {
    int bid = blockIdx.x;
    int e = ((bid & 7) << 6) | (bid >> 3);  // XCD gets contiguous span
    int ct = e >> 2, bt = (e >> 1) & 1, jh = e & 1;
    __shared__ __align__(16) char lds[49152];
    char* lB = lds;  // 32 KB swizzled H tile
    int t = threadIdx.x;
    const unsigned short* Bg = H + (size_t)(ct * 128) * NL;
    for (int i = t; i < 2048; i += 256) {
        int row = i >> 4, c = i & 15;
        int sw = (c * 16) ^ ((row & 7) << 4);
        *(bf16x8_t*)(lB + row * 256 + sw) =
            *(const bf16x8_t*)(Bg + (size_t)row * NL + c * 8);
    }
    __syncthreads();
    int w = t >> 6, lane = t & 63;
    int wr = (w >> 1) * 64;   // wave b-row offset
    int wc = (w & 1) * 64;    // wave col offset
    int r = lane & 15, g = lane >> 4;
    char* slab = lds + 32768 + w * 4096;  // wave-private 4 KB bounce

    for (int mf = 0; mf < 4; ++mf) {
        int brow_base = bt * 128 + wr + mf * 16;
#pragma unroll
        for (int g0 = 0; g0 < 2; ++g0) {
            // hoist A fragments: av[jj4][kk], loaded once per (mf,g0)
            bf16x8_t av[4][4];
#pragma unroll
            for (int jj4 = 0; jj4 < 4; ++jj4) {
                int j = jh * 8 + g0 * 4 + jj4;
                const unsigned short* Arow =
                    Cc + (size_t)j * CMS + (size_t)(brow_base + r) * NL;
#pragma unroll
                for (int kk = 0; kk < 4; ++kk)
                    av[jj4][kk] = *(const bf16x8_t*)(Arow + (kk * 4 + g) * 8);
            }
            for (int nf = 0; nf < 4; ++nf) {
                int nn = (w & 1) * 4 + nf;
                int rowB = wc + nf * 16 + r;
                // hoist B fragments per nf
                bf16x8_t bvv[4];
#pragma unroll
                for (int kk = 0; kk < 4; ++kk)
                    bvv[kk] = *(const bf16x8_t*)(
                        lB + rowB * 256 + (((kk * 4 + g) * 16) ^ ((rowB & 7) << 4)));
                f32x4_t acc4[4];
#pragma unroll
                for (int q = 0; q < 4; ++q) acc4[q] = (f32x4_t){0.f, 0.f, 0.f, 0.f};
#pragma unroll
                for (int jj4 = 0; jj4 < 4; ++jj4)
#pragma unroll
                    for (int kk = 0; kk < 4; ++kk)
                        acc4[jj4] = __builtin_amdgcn_mfma_f32_16x16x32_bf16(
                            bvv[kk], av[jj4][kk], acc4[jj4], 0, 0, 0);
                // bounce: slab[r][col], col rotated by r*32B (2-way banks)
#pragma unroll
                for (int jj4 = 0; jj4 < 4; ++jj4) {
                    int boff = r * 256 + ((jj4 * 64 + g * 16 + r * 32) & 255);
                    *(f32x4_t*)(slab + boff) = acc4[jj4];
                }
                // read back + contiguous normal stores (256B runs)
#pragma unroll
                for (int i2 = 0; i2 < 4; ++i2) {
                    int lin = i2 * 1024 + lane * 16;
                    int rs = lin >> 8, cb = lin & 255;
                    f32x4_t v = *(const f32x4_t*)(slab + rs * 256 + ((cb + rs * 32) & 255));
                    size_t o = (size_t)(brow_base + rs) * (NIN * 256) +
                               (size_t)(ct * 8 + nn) * 256 + jh * 128 + g0 * 64 + (cb >> 2);
                    *(f32x4_t*)&out[o] = v;
                }
            }
        }
    }
}

extern "C" void kernel_launch(void* const* d_in, const int* in_sizes, int n_in,
                              void* d_out, int out_size, void* d_ws, size_t ws_size,
                              hipStream_t stream) {
    const float* x = (const float*)d_in[0];
    const float* tf = (const float*)d_in[1];
    const float* tr = (const float*)d_in[2];
    float* out = (float*)d_out;

    // workspace (~9 MB)
    float* W = (float*)d_ws;                              // 20 f32 slots
    float* Cf = W + (size_t)20 * MS;                      // 16 x [256][128] f32
    unsigned short* Wb = (unsigned short*)(Cf + (size_t)16 * CMS);  // 16 bf16 slots
    unsigned short* Fb = Wb + (size_t)16 * MS;            // [1024][128] bf16
    unsigned short* Cc = Fb + (size_t)NIN * NL;           // 16 x [256][128] bf16
    unsigned short* H = Cc + (size_t)16 * CMS;            // [16384][128] bf16 (4 MB)

    static const int grids[8] = {104, 16, 32, 64, 152, 40, 72, 136};
    for (int ph = 0; ph < 8; ++ph) {
        k_phase<<<grids[ph], 256, 0, stream>>>(ph, x, tf, tr, W, Wb, Fb,
                                               Cf, Cc, H);
    }
    k_main<<<512, 256, 0, stream>>>(Cc, H, out);
}